// Round 2
// baseline (254.029 us; speedup 1.0000x reference)
//
#include <hip/hip_runtime.h>
#include <stdint.h>

typedef unsigned int u32;
typedef unsigned short u16;

#define N_  1024
#define F_  512
#define ALPHA 0.2f
#define MSTR 36   // LDS row stride (u16 elems) for transposed X tile: 72B rows, b64-aligned

typedef __attribute__((ext_vector_type(8))) short short8;
typedef __attribute__((ext_vector_type(4))) float float4v;

union Frag { short8 s; u32 u[4]; };

static __device__ __forceinline__ float bits2f(u32 b){ union{u32 u; float f;} c; c.u=b; return c.f; }
static __device__ __forceinline__ u32   f2bits(float f){ union{float f_; u32 u;} c; c.f_=f; return c.u; }
static __device__ __forceinline__ float bflo(u32 p){ return bits2f(p<<16); }
static __device__ __forceinline__ float bfhi(u32 p){ return bits2f(p & 0xffff0000u); }
static __device__ __forceinline__ u32   f2bf(float f){ u32 u=f2bits(f); return (u + 0x7fffu + ((u>>16)&1u))>>16; }

// ---- kernel 0: dtype detector. Low u16 of each word as bf16: exponent >= 0x8E
// (|v| >= 2^15, incl. NaN/Inf) is impossible for bf16 N(0,1) data, near-certain
// (per 64 samples) for fp32 mantissa bits. flag=1 -> inputs are fp32.
__global__ void k_detect(const u32* __restrict__ Xw, int* __restrict__ flag){
    u32 w = Xw[threadIdx.x];
    u32 e = (w >> 7) & 0xffu;
    unsigned long long m = __ballot(e >= 0x8eu);
    if(threadIdx.x == 0) flag[0] = (m != 0ULL) ? 1 : 0;
}

// ---- kernel 1: w1 = W^T a1, w2 = W^T a2 (atomic partial sums into ws[0..1024)) ----
__global__ void k_w12(const void* __restrict__ Wv, const void* __restrict__ a1v,
                      const void* __restrict__ a2v, float* __restrict__ ws,
                      const int* __restrict__ flag){
    int t = threadIdx.x;          // 256 threads: f = t and t+256
    int bo = blockIdx.x;          // 64 blocks: o-chunk of 8
    int isf = *flag;
    float s1a=0.f,s2a=0.f,s1b=0.f,s2b=0.f;
    if(isf){
        const float* W  = (const float*)Wv;
        const float* a1 = (const float*)a1v;
        const float* a2 = (const float*)a2v;
        #pragma unroll
        for(int i=0;i<8;i++){
            int o = bo*8+i;
            float av1 = a1[o], av2 = a2[o];
            float wa = W[o*F_ + t], wb = W[o*F_ + t + 256];
            s1a += wa*av1; s2a += wa*av2; s1b += wb*av1; s2b += wb*av2;
        }
    } else {
        const u16* W  = (const u16*)Wv;
        const u16* a1 = (const u16*)a1v;
        const u16* a2 = (const u16*)a2v;
        #pragma unroll
        for(int i=0;i<8;i++){
            int o = bo*8+i;
            float av1 = bflo((u32)a1[o]), av2 = bflo((u32)a2[o]);
            float wa = bflo((u32)W[o*F_ + t]), wb = bflo((u32)W[o*F_ + t + 256]);
            s1a += wa*av1; s2a += wa*av2; s1b += wb*av1; s2b += wb*av2;
        }
    }
    atomicAdd(&ws[t],       s1a); atomicAdd(&ws[512+t],     s2a);
    atomicAdd(&ws[t+256],   s1b); atomicAdd(&ws[512+t+256], s2b);
}

// ---- kernel 2: per-row f1,f2 -> exp tables ----
__global__ void k_rowstats(const void* __restrict__ Xv, const float* __restrict__ ws,
                           float* __restrict__ e1p, float* __restrict__ e1n,
                           u32* __restrict__ e2pn, const int* __restrict__ flag){
    int lane = threadIdx.x & 63;
    int wv   = threadIdx.x >> 6;
    int r    = blockIdx.x*4 + wv;            // 0..16383
    int isf  = *flag;
    float xf[8];
    if(isf){
        const float* Xf = (const float*)Xv;
        float4 A = *(const float4*)(Xf + (size_t)r*F_ + lane*8);
        float4 Bq = *(const float4*)(Xf + (size_t)r*F_ + lane*8 + 4);
        xf[0]=A.x; xf[1]=A.y; xf[2]=A.z; xf[3]=A.w;
        xf[4]=Bq.x; xf[5]=Bq.y; xf[6]=Bq.z; xf[7]=Bq.w;
    } else {
        const u16* X = (const u16*)Xv;
        const uint4 xv = *(const uint4*)(X + (size_t)r*F_ + lane*8);
        const u32* xw = (const u32*)&xv;
        #pragma unroll
        for(int k=0;k<4;k++){ xf[2*k] = bflo(xw[k]); xf[2*k+1] = bfhi(xw[k]); }
    }
    float4 wA = *(const float4*)(ws + lane*8);
    float4 wB = *(const float4*)(ws + lane*8 + 4);
    float4 vA = *(const float4*)(ws + 512 + lane*8);
    float4 vB = *(const float4*)(ws + 512 + lane*8 + 4);
    float d1 = xf[0]*wA.x + xf[1]*wA.y + xf[2]*wA.z + xf[3]*wA.w
             + xf[4]*wB.x + xf[5]*wB.y + xf[6]*wB.z + xf[7]*wB.w;
    float d2 = xf[0]*vA.x + xf[1]*vA.y + xf[2]*vA.z + xf[3]*vA.w
             + xf[4]*vB.x + xf[5]*vB.y + xf[6]*vB.z + xf[7]*vB.w;
    #pragma unroll
    for(int k=32;k>=1;k>>=1){ d1 += __shfl_xor(d1,k,64); d2 += __shfl_xor(d2,k,64); }
    if(lane==0){
        e1p[r] = __expf(d1);
        e1n[r] = __expf(ALPHA*d1);
        u32 lo = f2bf(__expf(d2));
        u32 hi = f2bf(__expf(ALPHA*d2));
        e2pn[r] = lo | (hi<<16);
    }
}

// ---- kernel 3: fused scores+softmax+PV+ELU ----
// grid (32 n-blocks, 16 b), block 128 (2 waves). wave: 16 n-rows x 512 f. m-chunks of 32.
__global__ __launch_bounds__(128)
void k_main(const void* __restrict__ Xv, const int* __restrict__ adj,
            const float* __restrict__ e1p, const float* __restrict__ e1n,
            const u32* __restrict__ e2pn, void* __restrict__ outv,
            const int* __restrict__ flag){
    __shared__ u16 lds_xt[F_*MSTR];   // X tile transposed: [f][m], 36864 B
    __shared__ u32 lds_e2[N_];        // packed exp(f2) pairs, 4096 B
    __shared__ float sden[32];

    const int t    = threadIdx.x;
    const int lane = t & 63;
    const int wv   = t >> 6;
    const int b    = blockIdx.y;
    const int n0   = blockIdx.x * 32;
    const int row16 = lane & 15;
    const int quad  = lane >> 4;
    const int n_row = n0 + wv*16 + row16;
    const int isf   = *flag;

    {   // stage exp(f2) pairs for this batch
        const uint4* src = (const uint4*)(e2pn + (size_t)b*N_);
        uint4* dst = (uint4*)lds_e2;
        dst[t]     = src[t];
        dst[t+128] = src[t+128];
    }
    const float e1pR = e1p[b*N_ + n_row];
    const float e1nR = e1n[b*N_ + n_row];
    const int* adjRow = adj + ((size_t)(b*N_ + n_row))*N_ + quad*8;

    float4v acc[32];
    #pragma unroll
    for(int i=0;i<32;i++) acc[i] = (float4v){0.f,0.f,0.f,0.f};
    float dsum = 0.f;

    const int foBase = (t&7) + ((t>>6)<<3);  // + q*16 -> f-octet 0..63
    const int uu     = (t>>3)&7;             // m-unit (4 rows)

    for(int m0=0; m0<N_; m0+=32){
        __syncthreads();
        // ---- stage X[b][m0..m0+32)[:] transposed into LDS (as bf16) ----
        if(isf){
            const float* Xf = ((const float*)Xv) + (size_t)b*N_*F_;
            #pragma unroll
            for(int q=0;q<4;q++){
                int fo = foBase + q*16;
                const float* sp = Xf + (size_t)(m0 + uu*4)*F_ + fo*8;
                float r0[8], r1[8], r2[8], r3[8];
                *(float4*)r0 = *(const float4*)sp;          *(float4*)(r0+4) = *(const float4*)(sp+4);
                *(float4*)r1 = *(const float4*)(sp+F_);     *(float4*)(r1+4) = *(const float4*)(sp+F_+4);
                *(float4*)r2 = *(const float4*)(sp+2*F_);   *(float4*)(r2+4) = *(const float4*)(sp+2*F_+4);
                *(float4*)r3 = *(const float4*)(sp+3*F_);   *(float4*)(r3+4) = *(const float4*)(sp+3*F_+4);
                #pragma unroll
                for(int j=0;j<8;j++){
                    uint2 val;
                    val.x = f2bf(r0[j]) | (f2bf(r1[j])<<16);
                    val.y = f2bf(r2[j]) | (f2bf(r3[j])<<16);
                    *(uint2*)(lds_xt + (size_t)(fo*8+j)*MSTR + uu*4) = val;
                }
            }
        } else {
            const u16* Xb = ((const u16*)Xv) + (size_t)b*N_*F_;
            #pragma unroll
            for(int q=0;q<4;q++){
                int fo = foBase + q*16;
                const u16* srcp = Xb + (size_t)(m0 + uu*4)*F_ + fo*8;
                u32 c0[4], c1[4], c2[4], c3[4];
                *(uint4*)c0 = *(const uint4*)(srcp);
                *(uint4*)c1 = *(const uint4*)(srcp + F_);
                *(uint4*)c2 = *(const uint4*)(srcp + 2*F_);
                *(uint4*)c3 = *(const uint4*)(srcp + 3*F_);
                #pragma unroll
                for(int j=0;j<8;j++){
                    int w = j>>1;
                    u32 sel = (j&1) ? 0x07060302u : 0x05040100u;
                    uint2 val;
                    val.x = __builtin_amdgcn_perm(c1[w], c0[w], sel);
                    val.y = __builtin_amdgcn_perm(c3[w], c2[w], sel);
                    *(uint2*)(lds_xt + (size_t)(fo*8+j)*MSTR + uu*4) = val;
                }
            }
        }
        __syncthreads();
        // ---- P generation in A-fragment layout ----
        int ad[8];
        *(int4*)(ad)   = *(const int4*)(adjRow + m0);
        *(int4*)(ad+4) = *(const int4*)(adjRow + m0 + 4);
        u32 ev[8];
        *(uint4*)(ev)   = *(const uint4*)(&lds_e2[m0 + quad*8]);
        *(uint4*)(ev+4) = *(const uint4*)(&lds_e2[m0 + quad*8 + 4]);
        u32 pb[8];
        #pragma unroll
        for(int j=0;j<8;j++){
            float pp = e1pR * bflo(ev[j]);
            float pn = e1nR * bfhi(ev[j]);
            float p  = (pp > 1.0f) ? pp : pn;
            p = (ad[j] != 0) ? p : 0.0f;
            dsum += p;
            pb[j] = f2bf(p);
        }
        Frag af;
        af.u[0] = pb[0] | (pb[1]<<16);
        af.u[1] = pb[2] | (pb[3]<<16);
        af.u[2] = pb[4] | (pb[5]<<16);
        af.u[3] = pb[6] | (pb[7]<<16);
        // ---- 32 MFMAs over the 512 f columns ----
        #pragma unroll
        for(int ct=0; ct<32; ct++){
            const u16* bp = lds_xt + (size_t)(ct*16 + row16)*MSTR + quad*8;
            uint2 blo = *(const uint2*)bp;
            uint2 bhi = *(const uint2*)(bp + 4);
            Frag bf_;
            bf_.u[0]=blo.x; bf_.u[1]=blo.y; bf_.u[2]=bhi.x; bf_.u[3]=bhi.y;
            acc[ct] = __builtin_amdgcn_mfma_f32_16x16x32_bf16(af.s, bf_.s, acc[ct], 0, 0, 0);
        }
    }
    // ---- softmax denominator ----
    dsum += __shfl_xor(dsum, 16, 64);
    dsum += __shfl_xor(dsum, 32, 64);
    if(lane < 16) sden[wv*16 + row16] = dsum;
    __syncthreads();
    float inv[4];
    #pragma unroll
    for(int r=0;r<4;r++) inv[r] = 1.0f / fmaxf(sden[wv*16 + quad*4 + r], 1e-30f);
    // ---- epilogue: scale, ELU, store in detected dtype ----
    if(isf){
        float* outf = (float*)outv;
        #pragma unroll
        for(int ct=0; ct<32; ct++){
            #pragma unroll
            for(int r=0;r<4;r++){
                float v = acc[ct][r] * inv[r];
                v = (v > 0.f) ? v : (__expf(v) - 1.f);
                int n_out = n0 + wv*16 + quad*4 + r;
                outf[((size_t)(b*N_ + n_out))*F_ + ct*16 + row16] = v;
            }
        }
    } else {
        u16* outb = (u16*)outv;
        #pragma unroll
        for(int ct=0; ct<32; ct++){
            #pragma unroll
            for(int r=0;r<4;r++){
                float v = acc[ct][r] * inv[r];
                v = (v > 0.f) ? v : (__expf(v) - 1.f);
                int n_out = n0 + wv*16 + quad*4 + r;
                outb[((size_t)(b*N_ + n_out))*F_ + ct*16 + row16] = (u16)f2bf(v);
            }
        }
    }
}

extern "C" void kernel_launch(void* const* d_in, const int* in_sizes, int n_in,
                              void* d_out, int out_size, void* d_ws, size_t ws_size,
                              hipStream_t stream) {
    const void* X  = d_in[0];              // [16,1024,512] fp32 or bf16
    const int* adj = (const int*)d_in[1];  // [16,1024,1024] int32
    const void* W  = d_in[2];              // [512,512]
    const void* a1 = d_in[3];              // [512]
    const void* a2 = d_in[4];              // [512]
    float* ws  = (float*)d_ws;
    float* e1p = ws + 1024;
    float* e1n = ws + 1024 + 16384;
    u32*  e2pn = (u32*)(ws + 1024 + 32768);
    int*  flag = (int*)(ws + 1024 + 49152);

    hipMemsetAsync(ws, 0, 1024*sizeof(float), stream);   // zero w1/w2 accumulators
    k_detect<<<1, 64, 0, stream>>>((const u32*)X, flag);
    k_w12<<<64, 256, 0, stream>>>(W, a1, a2, ws, flag);
    k_rowstats<<<4096, 256, 0, stream>>>(X, ws, e1p, e1n, e2pn, flag);
    k_main<<<dim3(32,16), 128, 0, stream>>>(X, adj, e1p, e1n, e2pn, d_out, flag);
}